// Round 1
// baseline (266.553 us; speedup 1.0000x reference)
//
#include <hip/hip_runtime.h>
#include <math.h>

#define N 10000
#define DIN 256
#define DOUT 128
#define C0 1.6487212707001282f   // exp(sigmoid(0)) = exp(0.5)

// ---------------- K1: WH = relu(H @ W^T + b); also s, r, colsum ----------------
// block = 256 threads, tile = 32 rows x 128 cols, thread tile 4x4, K chunked by 64
__global__ __launch_bounds__(256) void k_gemm(
        const float* __restrict__ H, const float* __restrict__ W,
        const float* __restrict__ Wb,
        const float* __restrict__ vt, const float* __restrict__ vtb,
        const float* __restrict__ vr, const float* __restrict__ vrb,
        float* __restrict__ WH, float* __restrict__ s_out, float* __restrict__ r_out,
        float* __restrict__ colsum)
{
    __shared__ float hs[32 * 260];   // H tile [32][256] padded to 260
    __shared__ float wt[64 * 132];   // W^T chunk [64][128] padded to 132; reused as WH tile
    const int t = threadIdx.x;
    const int brow = blockIdx.x * 32;

    // load H tile (zero-fill ghost rows)
    #pragma unroll
    for (int l = 0; l < 8; ++l) {
        int fid = t + l * 256;          // 0..2047 float4 slots
        int row = fid >> 6;             // 0..31
        int f4  = fid & 63;             // 0..63
        int grow = brow + row;
        float4 v = make_float4(0.f, 0.f, 0.f, 0.f);
        if (grow < N) v = *(const float4*)(H + (size_t)grow * DIN + f4 * 4);
        *(float4*)(hs + row * 260 + f4 * 4) = v;
    }

    float acc[4][4];
    #pragma unroll
    for (int i = 0; i < 4; ++i)
        #pragma unroll
        for (int j = 0; j < 4; ++j) acc[i][j] = 0.f;

    const int tx = t & 31;   // col group: cols tx*4..tx*4+3
    const int ty = t >> 5;   // row group: rows ty*4..ty*4+3

    for (int kc = 0; kc < 4; ++kc) {
        __syncthreads();
        // load W chunk transposed: wt[k][col] for k in [0,64)
        #pragma unroll
        for (int l = 0; l < 8; ++l) {
            int fid = t + l * 256;       // 0..2047
            int col = fid >> 4;          // 0..127
            int kq  = fid & 15;          // 0..15 (float4 within 64-chunk)
            float4 v = *(const float4*)(W + (size_t)col * DIN + kc * 64 + kq * 4);
            wt[(kq * 4 + 0) * 132 + col] = v.x;
            wt[(kq * 4 + 1) * 132 + col] = v.y;
            wt[(kq * 4 + 2) * 132 + col] = v.z;
            wt[(kq * 4 + 3) * 132 + col] = v.w;
        }
        __syncthreads();
        #pragma unroll 4
        for (int k = 0; k < 64; ++k) {
            float4 w4 = *(const float4*)(wt + k * 132 + tx * 4);
            int gk = kc * 64 + k;
            float h0 = hs[(ty * 4 + 0) * 260 + gk];
            float h1 = hs[(ty * 4 + 1) * 260 + gk];
            float h2 = hs[(ty * 4 + 2) * 260 + gk];
            float h3 = hs[(ty * 4 + 3) * 260 + gk];
            acc[0][0] += h0 * w4.x; acc[0][1] += h0 * w4.y; acc[0][2] += h0 * w4.z; acc[0][3] += h0 * w4.w;
            acc[1][0] += h1 * w4.x; acc[1][1] += h1 * w4.y; acc[1][2] += h1 * w4.z; acc[1][3] += h1 * w4.w;
            acc[2][0] += h2 * w4.x; acc[2][1] += h2 * w4.y; acc[2][2] += h2 * w4.z; acc[2][3] += h2 * w4.w;
            acc[3][0] += h3 * w4.x; acc[3][1] += h3 * w4.y; acc[3][2] += h3 * w4.z; acc[3][3] += h3 * w4.w;
        }
    }

    __syncthreads();   // done reading wt as W; reuse as WH tile [32][132]
    float4 bias = *(const float4*)(Wb + tx * 4);
    #pragma unroll
    for (int i = 0; i < 4; ++i) {
        int row = ty * 4 + i;
        int grow = brow + row;
        float4 o;
        o.x = fmaxf(acc[i][0] + bias.x, 0.f);
        o.y = fmaxf(acc[i][1] + bias.y, 0.f);
        o.z = fmaxf(acc[i][2] + bias.z, 0.f);
        o.w = fmaxf(acc[i][3] + bias.w, 0.f);
        *(float4*)(wt + row * 132 + tx * 4) = o;
        if (grow < N) *(float4*)(WH + (size_t)grow * DOUT + tx * 4) = o;
    }
    __syncthreads();

    // s, r: one wave per 8 rows; lane handles 2 cols
    const int wv = t >> 6, ln = t & 63;
    float vt0 = vt[2 * ln], vt1 = vt[2 * ln + 1];
    float vr0 = vr[2 * ln], vr1 = vr[2 * ln + 1];
    for (int rr = 0; rr < 8; ++rr) {
        int row = wv * 8 + rr;
        float a = wt[row * 132 + 2 * ln];
        float b = wt[row * 132 + 2 * ln + 1];
        float sp = a * vt0 + b * vt1;
        float rp = a * vr0 + b * vr1;
        #pragma unroll
        for (int off = 32; off; off >>= 1) {
            sp += __shfl_xor(sp, off);
            rp += __shfl_xor(rp, off);
        }
        int grow = brow + row;
        if (ln == 0 && grow < N) {
            s_out[grow] = sp + vtb[0];
            r_out[grow] = rp + vrb[0];
        }
    }

    // column sums (only valid rows)
    if (t < 128) {
        float cs = 0.f;
        int nvalid = N - brow; if (nvalid > 32) nvalid = 32;
        for (int rr = 0; rr < nvalid; ++rr) cs += wt[rr * 132 + t];
        atomicAdd(&colsum[t], cs);
    }
}

// ---------------- K2: scan dense A, emit sparse (row, col, delta) ----------------
__global__ void k_scan(const float* __restrict__ A, const float* __restrict__ s,
                       const float* __restrict__ r, int* __restrict__ rowcount,
                       int2* __restrict__ rowdata, int cap)
{
    size_t tid = (size_t)blockIdx.x * blockDim.x + threadIdx.x;
    size_t stride = (size_t)gridDim.x * blockDim.x;
    const size_t total4 = (size_t)N * N / 4;
    for (size_t i = tid; i < total4; i += stride) {
        float4 v = ((const float4*)A)[i];
        float vv[4] = {v.x, v.y, v.z, v.w};
        #pragma unroll
        for (int j = 0; j < 4; ++j) {
            if (vv[j] != 0.0f) {
                unsigned e = (unsigned)(i * 4) + j;
                int p = (int)(e / (unsigned)N);
                int q = (int)(e % (unsigned)N);
                float b = A[(size_t)q * N + p];     // symmetric probe for dedup
                // full M[p,q] = s[q] + (A[q,p]!=0 ? r[p] : 0)
                float m = s[q] + ((b != 0.f) ? r[p] : 0.f);
                float sg = 1.f / (1.f + expf(-m));
                float d1 = expf(sg) - C0;
                int pos = atomicAdd(&rowcount[p], 1);
                if (pos < cap) rowdata[(size_t)p * cap + pos] = make_int2(q, __float_as_int(d1));
                if (b == 0.f) {
                    // r-only entry M[q,p] = r[q]; emitted here exactly once
                    float m2 = r[q];
                    float sg2 = 1.f / (1.f + expf(-m2));
                    float d2 = expf(sg2) - C0;
                    int pos2 = atomicAdd(&rowcount[q], 1);
                    if (pos2 < cap) rowdata[(size_t)q * cap + pos2] = make_int2(p, __float_as_int(d2));
                }
            }
        }
    }
}

// ---------------- K3: per-row gather: out[i] = (c*colsum + sum d*WH[j]) / (c*N + sum d) ----------------
__global__ __launch_bounds__(256) void k_out(const float* __restrict__ WH,
        const float* __restrict__ colsum, const int* __restrict__ rowcount,
        const int2* __restrict__ rowdata, int cap, float* __restrict__ out)
{
    const int wv = threadIdx.x >> 6, ln = threadIdx.x & 63;
    int row = blockIdx.x * 4 + wv;
    if (row >= N) return;
    int n = rowcount[row]; if (n > cap) n = cap;
    const int d = 2 * ln;
    float acc0 = C0 * colsum[d];
    float acc1 = C0 * colsum[d + 1];
    float z = C0 * (float)N;
    const int2* rd = rowdata + (size_t)row * cap;
    for (int e = 0; e < n; ++e) {
        int2 en = rd[e];
        float dl = __int_as_float(en.y);
        const float* wrow = WH + (size_t)en.x * DOUT;
        acc0 += dl * wrow[d];
        acc1 += dl * wrow[d + 1];
        z += dl;
    }
    float inv = 1.f / z;
    out[(size_t)row * DOUT + d]     = acc0 * inv;
    out[(size_t)row * DOUT + d + 1] = acc1 * inv;
}

extern "C" void kernel_launch(void* const* d_in, const int* in_sizes, int n_in,
                              void* d_out, int out_size, void* d_ws, size_t ws_size,
                              hipStream_t stream)
{
    const float* H   = (const float*)d_in[0];
    const float* A   = (const float*)d_in[1];
    const float* W   = (const float*)d_in[2];
    const float* Wb  = (const float*)d_in[3];
    const float* vt  = (const float*)d_in[4];
    const float* vtb = (const float*)d_in[5];
    const float* vr  = (const float*)d_in[6];
    const float* vrb = (const float*)d_in[7];

    char* ws = (char*)d_ws;
    size_t off = 0;
    float* WH = (float*)(ws + off);      off += (size_t)N * DOUT * 4;   // 5,120,000
    float* s_ = (float*)(ws + off);      off += 40960;
    float* r_ = (float*)(ws + off);      off += 40960;
    size_t zero_off = off;
    float* colsum = (float*)(ws + off);  off += 1024;
    int* rowcount = (int*)(ws + off);    off += 40960;
    size_t zero_len = off - zero_off;
    int2* rowdata = (int2*)(ws + off);
    size_t avail = (ws_size > off) ? (ws_size - off) : 0;
    int cap = (int)(avail / ((size_t)N * 8));
    if (cap > 160) cap = 160;   // Poisson(~60) entries/row; 160 is > +12 sigma

    hipMemsetAsync(ws + zero_off, 0, zero_len, stream);
    k_gemm<<<(N + 31) / 32, 256, 0, stream>>>(H, W, Wb, vt, vtb, vr, vrb, WH, s_, r_, colsum);
    k_scan<<<2048, 256, 0, stream>>>(A, s_, r_, rowcount, rowdata, cap);
    k_out<<<(N + 3) / 4, 256, 0, stream>>>(WH, colsum, rowcount, rowdata, cap, (float*)d_out);
}